// Round 14
// baseline (4281.178 us; speedup 1.0000x reference)
//
#include <hip/hip_runtime.h>
#include <hip/hip_bf16.h>

#define BB 8
#define TT 512
#define KK 8
#define HH 128
#define G3 384
#define DIN 100
#define DG 50
#define NL 20

#if __has_builtin(__builtin_amdgcn_rcpf)
#define RCP_(x) __builtin_amdgcn_rcpf(x)
#else
#define RCP_(x) (1.0f/(x))
#endif

__device__ __forceinline__ float fexp_(float x) { return __expf(x); }
__device__ __forceinline__ float fsig_(float x) { return RCP_(1.0f + __expf(-x)); }
__device__ __forceinline__ float ftanh_(float x) {
    float e = __expf(2.0f * x);          // saturates correctly: inf -> 1, 0 -> -1
    return 1.0f - 2.0f * RCP_(e + 1.0f);
}
// LDS-ordering barrier that does NOT drain vmcnt (prefetches stay in flight)
__device__ __forceinline__ void barrier_() {
    asm volatile("s_waitcnt lgkmcnt(0)\n\ts_barrier" ::: "memory");
}

// ---------------- kernel 1a: g3x = x @ W_ih^T + b_lstm ; alphax = x @ Wa_ih^T + b_alpha
__global__ __launch_bounds__(512, 1)
void embed_gates_kernel(const int* __restrict__ wid, const int* __restrict__ bwid,
                        const float* __restrict__ wtab, const float* __restrict__ bwtab,
                        const float* __restrict__ Wih, const float* __restrict__ Waih,
                        const float* __restrict__ bl, const float* __restrict__ ba,
                        float* __restrict__ g3x, float* __restrict__ axo,
                        int c0, int CH)
{
    __shared__ float xs[8][104];
    const int tid = threadIdx.x;
    const int bpg = CH >> 3;
    const int b = blockIdx.x / bpg;
    const int tg = blockIdx.x % bpg;
    const int t0 = c0 + tg * 8;

    for (int idx = tid; idx < 800; idx += 512) {
        int tt = idx / 100;
        int c = idx - tt * 100;
        int t = t0 + tt;
        float v;
        if (c < 50) v = wtab[(long)wid[b * TT + t] * 50 + c];
        else        v = bwtab[(long)bwid[b * TT + t] * 50 + (c - 50)];
        xs[tt][c] = v;
    }
    __syncthreads();

    const int row = tid;
    float w[100];
    const float* wr;
    float bias;
    if (row < G3) { wr = Wih + (long)row * DIN; bias = bl[row]; }
    else          { wr = Waih + (long)(row - G3) * DIN; bias = ba[row - G3]; }
    const float4* wr4 = (const float4*)wr;
#pragma unroll
    for (int q = 0; q < 25; ++q) {
        float4 v = wr4[q];
        w[4*q] = v.x; w[4*q+1] = v.y; w[4*q+2] = v.z; w[4*q+3] = v.w;
    }
#pragma unroll 1
    for (int tt = 0; tt < 8; ++tt) {
        float a = bias;
#pragma unroll
        for (int c = 0; c < 100; ++c) a += w[c] * xs[tt][c];
        int lt = t0 - c0 + tt;
        if (row < G3) g3x[((long)b * CH + lt) * G3 + row] = a;
        else          axo[((long)b * CH + lt) * HH + (row - G3)] = a;
    }
}

// ---------------- kernel 1b: gwT[b][t][k][384] = Ww_ih @ gaz_emb + b_word
__global__ __launch_bounds__(384, 1)
void gaz_gates_kernel(const int* __restrict__ gids, const float* __restrict__ gtab,
                      const float* __restrict__ Wwih, const float* __restrict__ bw,
                      float* __restrict__ gwT, int c0, int CH)
{
    __shared__ float ges[64][52];
    const int tid = threadIdx.x;
    const int bpg = CH >> 3;
    const int b = blockIdx.x / bpg;
    const int tg = blockIdx.x % bpg;
    const int t0 = c0 + tg * 8;

    for (int idx = tid; idx < 64 * 50; idx += 384) {
        int p = idx / 50;
        int c = idx - p * 50;
        int tt = p >> 3, k = p & 7;
        int gid = gids[((long)(b * TT + t0 + tt)) * KK + k];
        ges[p][c] = gtab[(long)gid * DG + c];
    }
    __syncthreads();

    const int row = tid;
    float w[50];
    const float2* wr2 = (const float2*)(Wwih + (long)row * DG);
#pragma unroll
    for (int q = 0; q < 25; ++q) { float2 v = wr2[q]; w[2*q] = v.x; w[2*q+1] = v.y; }
    const float bias = bw[row];
    const int lt0 = t0 - c0;
#pragma unroll 1
    for (int p = 0; p < 64; ++p) {
        float a = bias;
#pragma unroll
        for (int c = 0; c < 50; ++c) a += w[c] * ges[p][c];
        int tt = p >> 3, k = p & 7;
        gwT[((long)(b * CH + lt0 + tt) * KK + k) * G3 + row] = a;
    }
}

// ---------------- kernel 2: sequential lattice scan, one block per batch
// 512 threads = 8 waves = 2 waves/SIMD. E1 weights (one full W2 row/thread)
// are STREAMED from L2 with SOURCE-LEVEL pipelining: 12 float4 chunks issued
// at the top of the step (they fly across B/C/D -- raw barriers don't drain
// vmcnt, and the "memory" clobber pins issue position), 16 more at E-start
// covered by E2's LDS work, last 4 at the end. Ww_hh rows 128..383 in LDS.
__global__ __attribute__((amdgpu_flat_work_group_size(512, 512), amdgpu_waves_per_eu(2, 2)))
void lattice_scan_kernel(const float* __restrict__ g3x, const float* __restrict__ axb,
                         const float* __restrict__ gwT, const int* __restrict__ gstarts,
                         const int* __restrict__ gmask,
                         const float* __restrict__ Whh, const float* __restrict__ Wwhh,
                         const float* __restrict__ Wahh,
                         float* __restrict__ hs, float* __restrict__ state,
                         int c0, int CH)
{
    __shared__ float cring[8][132];
    __shared__ float cwS[8][132];
    __shared__ float wwh[8][388];
    __shared__ float whh[G3];
    __shared__ float hcur[HH];
    __shared__ float vmkF[8];
    __shared__ float WwL[256 * 128];   // Ww_hh rows 128..383, swizzled

    const int t = threadIdx.x;
    const int b = blockIdx.x;
    const int lane = t & 63;
    const int kB = t >> 6;                 // wave id == gaz index k
    const int rq = t >> 2, q4 = t & 3;     // phase C/D mapping (row, quarter)
    const int rr = t >> 1, hE = t & 1;     // phase E LDS half-row mapping

    // Wa quarter-row registers (phase C, conflict-free quad interleave)
    float WAr[32];
#pragma unroll
    for (int i = 0; i < 8; ++i) {
        float4 v = *(const float4*)(Wahh + (long)rq * HH + 16 * i + 4 * q4);
        WAr[4*i]=v.x; WAr[4*i+1]=v.y; WAr[4*i+2]=v.z; WAr[4*i+3]=v.w;
    }
    // Ww_hh rows 128..383 -> LDS, swizzled 16B blocks (bijective per row)
    for (int idx = t; idx < 256 * 128; idx += 512) {
        int r = idx >> 7, c = idx & 127;
        int cblk = c >> 2;
        int sb = cblk ^ (r & 7) ^ ((cblk >> 4) << 2);
        WwL[r * 128 + (sb << 2) + (c & 3)] = Wwhh[(long)(128 + r) * HH + c];
    }
    // per-thread E1 weight-row base (rows 0..383 = W_hh, 384..511 = Ww rows 0..127)
    const float4* wrow4 = (t < G3) ? (const float4*)(Whh + (long)t * HH)
                                   : (const float4*)(Wwhh + (long)(t - G3) * HH);

    float* st = state + (long)b * 4480;  // cring 1024 | wwh 3072 | whh 384
    if (c0 == 0) {
        for (int idx = t; idx < 8 * 132; idx += 512) ((float*)cring)[idx] = 0.f;
        for (int idx = t; idx < 8 * 388; idx += 512) ((float*)wwh)[idx] = 0.f;
        for (int idx = t; idx < G3; idx += 512) whh[idx] = 0.f;
    } else {
        for (int idx = t; idx < 1024; idx += 512) cring[idx >> 7][idx & 127] = st[idx];
        for (int idx = t; idx < 3072; idx += 512) wwh[idx / 384][idx % 384] = st[1024 + idx];
        for (int idx = t; idx < 384; idx += 512) whh[idx] = st[4096 + idx];
    }
    barrier_();

    const long gwstep = (long)KK * G3;        // 3072
    const float* gwB = gwT + (long)b * CH * gwstep + (long)kB * G3 + 2 * lane;
    const long g3base = (long)b * CH * G3;
    const long axbase = (long)b * CH * HH;

    // ---- prefetch (step c0)
    float2 pA = *(const float2*)(gwB);
    float2 pF = *(const float2*)(gwB + 128);
    float2 pG = *(const float2*)(gwB + 256);
    int rs = gstarts[(b * TT + c0) * KK + kB];
    int rm = gmask  [(b * TT + c0) * KK + kB];
    float pg0 = g3x[g3base + rq];
    float pg1 = g3x[g3base + rq + 128];
    float pg2 = g3x[g3base + rq + 256];
    float pax = axb[axbase + rq];

    for (int j = c0; j < c0 + CH; ++j) {
        const int lt = j - c0;
        const int slot = rs & 7;                 // wave-uniform
        const bool valid = (rm != 0);
        const float2 cA = pA, cF = pF, cG = pG;
        const float dg0 = pg0, dg1 = pg1, dg2 = pg2, dax = pax;

        if (lane == 0) vmkF[kB] = valid ? 1.0f : 0.0f;

        // ---- issue E1 weight chunks 0..11 EARLY (latency/BW hidden under B/C/D)
        float4 wbufA[12];
#pragma unroll
        for (int i = 0; i < 12; ++i) wbufA[i] = wrow4[i];

        // ---- Phase B: word-LSTM cells; wave kB handles k=kB, 2 rows/lane
        {
            const int r2 = 2 * lane;
            float2 wi = *(const float2*)&wwh[slot][r2];
            float2 wf = *(const float2*)&wwh[slot][r2 + 128];
            float2 wg = *(const float2*)&wwh[slot][r2 + 256];
            float2 cs = *(const float2*)&cring[slot][r2];
            float2 cw;
            cw.x = fsig_(cF.x + wf.x) * cs.x + fsig_(cA.x + wi.x) * ftanh_(cG.x + wg.x);
            cw.y = fsig_(cF.y + wf.y) * cs.y + fsig_(cA.y + wi.y) * ftanh_(cG.y + wg.y);
            *(float2*)&cwS[kB][r2] = cw;
        }
        barrier_();

        // block-wide mask weights (broadcast reads)
        const float4 vk0 = *(const float4*)&vmkF[0];
        const float4 vk1 = *(const float4*)&vmkF[4];
        const float vmk[8] = {vk0.x, vk0.y, vk0.z, vk0.w, vk1.x, vk1.y, vk1.z, vk1.w};
        const bool hw_any = (vk0.x + vk0.y + vk0.z + vk0.w + vk1.x + vk1.y + vk1.z + vk1.w) > 0.f;

        // ---- Phase C: masked alpha aggregation; quad-interleaved, conflict-free
        float sumw = 0.f, sumwc = 0.f;
#pragma unroll
        for (int k = 0; k < 8; ++k) {
            if (vmk[k] != 0.f) {                 // wave-uniform branch
                float a0 = 0.f, a1 = 0.f;
#pragma unroll
                for (int i = 0; i < 8; i += 2) {
                    float4 c0v = *(const float4*)&cwS[k][16 * i + 4 * q4];
                    float4 c1v = *(const float4*)&cwS[k][16 * (i + 1) + 4 * q4];
                    a0 += WAr[4*i]*c0v.x + WAr[4*i+1]*c0v.y + WAr[4*i+2]*c0v.z + WAr[4*i+3]*c0v.w;
                    a1 += WAr[4*i+4]*c1v.x + WAr[4*i+5]*c1v.y + WAr[4*i+6]*c1v.z + WAr[4*i+7]*c1v.w;
                }
                float acc = a0 + a1;
                acc += __shfl_xor(acc, 1);       // combine quarters
                acc += __shfl_xor(acc, 2);
                float al = fsig_(dax + acc);
                float w = fexp_(al);
                sumw += w;
                sumwc += w * cwS[k][rq];
            }
        }

        // ---- next-step activation prefetch (after C to relieve register pressure;
        //      latency hides under D + E)
        if (lt + 1 < CH) {
            const float* gw = gwB + (long)(lt + 1) * gwstep;
            pA = *(const float2*)(gw);
            pF = *(const float2*)(gw + 128);
            pG = *(const float2*)(gw + 256);
            rs = gstarts[(b * TT + j + 1) * KK + kB];
            rm = gmask  [(b * TT + j + 1) * KK + kB];
            pg0 = g3x[g3base + (long)(lt + 1) * G3 + rq];
            pg1 = g3x[g3base + (long)(lt + 1) * G3 + rq + 128];
            pg2 = g3x[g3base + (long)(lt + 1) * G3 + rq + 256];
            pax = axb[axbase + (long)(lt + 1) * HH + rq];
        }

        // ---- Phase D: char cell + merge (4 lanes/row redundant, q4==0 writes)
        float i_ = fsig_(dg0 + whh[rq]);
        float o_ = fsig_(dg1 + whh[rq + 128]);
        float g_ = ftanh_(dg2 + whh[rq + 256]);
        float cprev = cring[(j - 1) & 7][rq];
        float wc = fexp_(i_);
        float csoft = (wc * g_ + sumwc) / (wc + sumw);
        float ccpl = (1.f - i_) * cprev + i_ * g_;
        float cn = hw_any ? csoft : ccpl;
        float hn = o_ * ftanh_(cn);
        if (q4 == 0) {
            cring[j & 7][rq] = cn;
            hcur[rq] = hn;
            hs[((long)b * CH + lt) * HH + rq] = hn;
        }
        barrier_();

        // ---- Phase E1a: consume early chunks (0..11), issue chunks 12..27
        const float4* h4 = (const float4*)hcur;
        float a0 = 0.f, a1 = 0.f, a2 = 0.f, a3 = 0.f;
#pragma unroll
        for (int i = 0; i < 12; ++i) {
            float4 w = wbufA[i], h = h4[i];
            a0 = fmaf(w.x, h.x, a0); a1 = fmaf(w.y, h.y, a1);
            a2 = fmaf(w.z, h.z, a2); a3 = fmaf(w.w, h.w, a3);
        }
        float4 wbufB[16];
#pragma unroll
        for (int i = 0; i < 16; ++i) wbufB[i] = wrow4[12 + i];

        // ---- Phase E2: LDS half-row dot (covers wbufB stream time)
        {
            float s0 = 0.f, s1 = 0.f;
#pragma unroll
            for (int cb = 0; cb < 16; cb += 2) {
                int cblk0 = cb | (hE << 4);
                int cblk1 = (cb + 1) | (hE << 4);
                int sb0 = cblk0 ^ (rr & 7) ^ (hE << 2);
                int sb1 = cblk1 ^ (rr & 7) ^ (hE << 2);
                float4 w0 = *(const float4*)&WwL[rr * 128 + (sb0 << 2)];
                float4 w1 = *(const float4*)&WwL[rr * 128 + (sb1 << 2)];
                float4 h0 = h4[cblk0], h1 = h4[cblk1];
                s0 += w0.x*h0.x + w0.y*h0.y + w0.z*h0.z + w0.w*h0.w;
                s1 += w1.x*h1.x + w1.y*h1.y + w1.z*h1.z + w1.w*h1.w;
            }
            float s = s0 + s1;
            s += __shfl_xor(s, 1);               // combine halves
            if (hE == 0) wwh[j & 7][128 + rr] = s;  // Ww rows 128..383
        }

        // ---- Phase E1b: consume chunks 12..27, issue+consume tail 28..31
        {
#pragma unroll
            for (int i = 0; i < 16; ++i) {
                float4 w = wbufB[i], h = h4[12 + i];
                a0 = fmaf(w.x, h.x, a0); a1 = fmaf(w.y, h.y, a1);
                a2 = fmaf(w.z, h.z, a2); a3 = fmaf(w.w, h.w, a3);
            }
#pragma unroll
            for (int i = 0; i < 4; ++i) {
                float4 w = wrow4[28 + i], h = h4[28 + i];
                a0 = fmaf(w.x, h.x, a0); a1 = fmaf(w.y, h.y, a1);
                a2 = fmaf(w.z, h.z, a2); a3 = fmaf(w.w, h.w, a3);
            }
            float e0 = (a0 + a1) + (a2 + a3);
            if (t < G3) whh[t] = e0;             // W_hh @ h (next char gates)
            else        wwh[j & 7][t - G3] = e0; // Ww rows 0..127
        }
        barrier_();
    }

    // persist state for next chunk
    for (int idx = t; idx < 1024; idx += 512) st[idx] = cring[idx >> 7][idx & 127];
    for (int idx = t; idx < 3072; idx += 512) st[1024 + idx] = wwh[idx / 384][idx % 384];
    for (int idx = t; idx < 384; idx += 512) st[4096 + idx] = whh[idx];
}

// ---------------- kernel 3: logits + argmax (fwd==bwd, so fold W_tag halves)
__global__ __launch_bounds__(320, 1)
void tag_kernel(const float* __restrict__ hs, const float* __restrict__ Wtag,
                const float* __restrict__ btag, const int* __restrict__ maskp,
                int* __restrict__ out, int c0, int CH)
{
    __shared__ float ht[16][132];
    __shared__ float lg[16][20];
    const int tid = threadIdx.x;
    const int bpg = CH >> 4;
    const int b = blockIdx.x / bpg;
    const int tg = blockIdx.x % bpg;
    const int lt0 = tg * 16;

    for (int idx = tid; idx < 16 * 128; idx += 320)
        ht[idx >> 7][idx & 127] = hs[((long)b * CH + lt0 + (idx >> 7)) * HH + (idx & 127)];
    __syncthreads();

    {
        int tl = tid / 20, l = tid - tl * 20;
        float a = btag[l];
        const float* w0 = Wtag + (long)l * 256;
#pragma unroll
        for (int r = 0; r < 128; ++r) a += (w0[r] + w0[r + 128]) * ht[tl][r];
        lg[tl][l] = a;
    }
    __syncthreads();
    if (tid < 16) {
        float best = lg[tid][0];
        int bi = 0;
#pragma unroll
        for (int l = 1; l < NL; ++l) {
            float v = lg[tid][l];
            if (v > best) { best = v; bi = l; }   // first-max (np.argmax semantics)
        }
        int t = c0 + lt0 + tid;
        out[b * TT + t] = maskp[b * TT + t] * bi;
    }
}

extern "C" void kernel_launch(void* const* d_in, const int* in_sizes, int n_in,
                              void* d_out, int out_size, void* d_ws, size_t ws_size,
                              hipStream_t stream) {
    const int* word_inputs   = (const int*)d_in[0];
    const int* biword_inputs = (const int*)d_in[1];
    const int* gaz_word_ids  = (const int*)d_in[2];
    const int* gaz_starts    = (const int*)d_in[3];
    const int* gaz_mask      = (const int*)d_in[4];
    const int* maskp         = (const int*)d_in[5];
    const float* word_table   = (const float*)d_in[6];
    const float* biword_table = (const float*)d_in[7];
    const float* gaz_table    = (const float*)d_in[8];
    const float* W_ih   = (const float*)d_in[9];
    const float* W_hh   = (const float*)d_in[10];
    const float* b_lstm = (const float*)d_in[11];
    const float* Wa_ih  = (const float*)d_in[12];
    const float* Wa_hh  = (const float*)d_in[13];
    const float* b_alpha= (const float*)d_in[14];
    const float* Ww_ih  = (const float*)d_in[15];
    const float* Ww_hh  = (const float*)d_in[16];
    const float* b_word = (const float*)d_in[17];
    const float* W_tag  = (const float*)d_in[18];
    const float* b_tag  = (const float*)d_in[19];
    int* out = (int*)d_out;
    float* ws = (float*)d_ws;

    // choose T-chunk so workspace fits: bytes = 118784*CH + 143360
    int CH = 16;
    if      (ws_size >= 118784UL * 512 + 143360UL) CH = 512;
    else if (ws_size >= 118784UL * 128 + 143360UL) CH = 128;
    else if (ws_size >= 118784UL *  32 + 143360UL) CH = 32;

    float* g3x = ws;                               // B*CH*384
    float* axb = g3x + 8L * CH * 384;              // B*CH*128
    float* gwT = axb + 8L * CH * 128;              // B*CH*8*384
    float* hsb = gwT + 8L * CH * 3072;             // B*CH*128
    float* stb = hsb + 8L * CH * 128;              // B*4480

    for (int c0 = 0; c0 < TT; c0 += CH) {
        embed_gates_kernel<<<CH, 512, 0, stream>>>(word_inputs, biword_inputs,
                                                   word_table, biword_table,
                                                   W_ih, Wa_ih, b_lstm, b_alpha,
                                                   g3x, axb, c0, CH);
        gaz_gates_kernel<<<CH, 384, 0, stream>>>(gaz_word_ids, gaz_table,
                                                 Ww_ih, b_word, gwT, c0, CH);
        lattice_scan_kernel<<<BB, 512, 0, stream>>>(g3x, axb, gwT, gaz_starts, gaz_mask,
                                                    W_hh, Ww_hh, Wa_hh, hsb, stb, c0, CH);
        tag_kernel<<<CH / 2, 320, 0, stream>>>(hsb, W_tag, b_tag, maskp, out, c0, CH);
    }
}

// Round 15
// 4280.717 us; speedup vs baseline: 1.0001x; 1.0001x over previous
//
#include <hip/hip_runtime.h>
#include <hip/hip_bf16.h>

#define BB 8
#define TT 512
#define KK 8
#define HH 128
#define G3 384
#define DIN 100
#define DG 50
#define NL 20

#if __has_builtin(__builtin_amdgcn_rcpf)
#define RCP_(x) __builtin_amdgcn_rcpf(x)
#else
#define RCP_(x) (1.0f/(x))
#endif

__device__ __forceinline__ float fexp_(float x) { return __expf(x); }
__device__ __forceinline__ float fsig_(float x) { return RCP_(1.0f + __expf(-x)); }
__device__ __forceinline__ float ftanh_(float x) {
    float e = __expf(2.0f * x);          // saturates correctly: inf -> 1, 0 -> -1
    return 1.0f - 2.0f * RCP_(e + 1.0f);
}
// LDS-ordering barrier that does NOT drain vmcnt (prefetches stay in flight)
__device__ __forceinline__ void barrier_() {
    asm volatile("s_waitcnt lgkmcnt(0)\n\ts_barrier" ::: "memory");
}

// ---------------- kernel 1a: g3x = x @ W_ih^T + b_lstm ; alphax = x @ Wa_ih^T + b_alpha
__global__ __launch_bounds__(512, 1)
void embed_gates_kernel(const int* __restrict__ wid, const int* __restrict__ bwid,
                        const float* __restrict__ wtab, const float* __restrict__ bwtab,
                        const float* __restrict__ Wih, const float* __restrict__ Waih,
                        const float* __restrict__ bl, const float* __restrict__ ba,
                        float* __restrict__ g3x, float* __restrict__ axo,
                        int c0, int CH)
{
    __shared__ float xs[8][104];
    const int tid = threadIdx.x;
    const int bpg = CH >> 3;
    const int b = blockIdx.x / bpg;
    const int tg = blockIdx.x % bpg;
    const int t0 = c0 + tg * 8;

    for (int idx = tid; idx < 800; idx += 512) {
        int tt = idx / 100;
        int c = idx - tt * 100;
        int t = t0 + tt;
        float v;
        if (c < 50) v = wtab[(long)wid[b * TT + t] * 50 + c];
        else        v = bwtab[(long)bwid[b * TT + t] * 50 + (c - 50)];
        xs[tt][c] = v;
    }
    __syncthreads();

    const int row = tid;
    float w[100];
    const float* wr;
    float bias;
    if (row < G3) { wr = Wih + (long)row * DIN; bias = bl[row]; }
    else          { wr = Waih + (long)(row - G3) * DIN; bias = ba[row - G3]; }
    const float4* wr4 = (const float4*)wr;
#pragma unroll
    for (int q = 0; q < 25; ++q) {
        float4 v = wr4[q];
        w[4*q] = v.x; w[4*q+1] = v.y; w[4*q+2] = v.z; w[4*q+3] = v.w;
    }
#pragma unroll 1
    for (int tt = 0; tt < 8; ++tt) {
        float a = bias;
#pragma unroll
        for (int c = 0; c < 100; ++c) a += w[c] * xs[tt][c];
        int lt = t0 - c0 + tt;
        if (row < G3) g3x[((long)b * CH + lt) * G3 + row] = a;
        else          axo[((long)b * CH + lt) * HH + (row - G3)] = a;
    }
}

// ---------------- kernel 1b: gwT[b][t][k][384] = Ww_ih @ gaz_emb + b_word
__global__ __launch_bounds__(384, 1)
void gaz_gates_kernel(const int* __restrict__ gids, const float* __restrict__ gtab,
                      const float* __restrict__ Wwih, const float* __restrict__ bw,
                      float* __restrict__ gwT, int c0, int CH)
{
    __shared__ float ges[64][52];
    const int tid = threadIdx.x;
    const int bpg = CH >> 3;
    const int b = blockIdx.x / bpg;
    const int tg = blockIdx.x % bpg;
    const int t0 = c0 + tg * 8;

    for (int idx = tid; idx < 64 * 50; idx += 384) {
        int p = idx / 50;
        int c = idx - p * 50;
        int tt = p >> 3, k = p & 7;
        int gid = gids[((long)(b * TT + t0 + tt)) * KK + k];
        ges[p][c] = gtab[(long)gid * DG + c];
    }
    __syncthreads();

    const int row = tid;
    float w[50];
    const float2* wr2 = (const float2*)(Wwih + (long)row * DG);
#pragma unroll
    for (int q = 0; q < 25; ++q) { float2 v = wr2[q]; w[2*q] = v.x; w[2*q+1] = v.y; }
    const float bias = bw[row];
    const int lt0 = t0 - c0;
#pragma unroll 1
    for (int p = 0; p < 64; ++p) {
        float a = bias;
#pragma unroll
        for (int c = 0; c < 50; ++c) a += w[c] * ges[p][c];
        int tt = p >> 3, k = p & 7;
        gwT[((long)(b * CH + lt0 + tt) * KK + k) * G3 + row] = a;
    }
}

// ---------------- kernel 2: sequential lattice scan, one block per batch
// ZERO-SPILL design: total register arrays = WAr(32) + Wq(32) -> fits the
// 128-reg budget with working set (~110 total). Work split:
//   E-reg: Ww rows 0..127 from Wq quarter-stash (regs) -- thread t = row t>>2,
//          quarter t&3 owns interleaved float4 blocks {4m + q4}.
//   E1:    W_hh rows 0..383 streamed from global (waves 0..5 only).
//   E2:    Ww rows 128..383 from LDS (128 KB, XOR-swizzled).
__global__ __attribute__((amdgpu_flat_work_group_size(512, 512), amdgpu_waves_per_eu(2, 2)))
void lattice_scan_kernel(const float* __restrict__ g3x, const float* __restrict__ axb,
                         const float* __restrict__ gwT, const int* __restrict__ gstarts,
                         const int* __restrict__ gmask,
                         const float* __restrict__ Whh, const float* __restrict__ Wwhh,
                         const float* __restrict__ Wahh,
                         float* __restrict__ hs, float* __restrict__ state,
                         int c0, int CH)
{
    __shared__ float cring[8][132];
    __shared__ float cwS[8][132];
    __shared__ float wwh[8][388];
    __shared__ float whh[G3];
    __shared__ float hcur[HH];
    __shared__ float vmkF[8];
    __shared__ float WwL[256 * 128];   // Ww_hh rows 128..383, swizzled

    const int t = threadIdx.x;
    const int b = blockIdx.x;
    const int lane = t & 63;
    const int kB = t >> 6;                 // wave id == gaz index k
    const int rq = t >> 2, q4 = t & 3;     // phase C/D/E-reg mapping (row, quarter)
    const int rr = t >> 1, hE = t & 1;     // phase E2 LDS half-row mapping

    // Wa quarter-row registers (phase C, conflict-free quad interleave)
    float WAr[32];
#pragma unroll
    for (int i = 0; i < 8; ++i) {
        float4 v = *(const float4*)(Wahh + (long)rq * HH + 16 * i + 4 * q4);
        WAr[4*i]=v.x; WAr[4*i+1]=v.y; WAr[4*i+2]=v.z; WAr[4*i+3]=v.w;
    }
    // Ww rows 0..127 quarter-stash: thread t = row t>>2 (=rq), blocks {4m+q4}
    float4 Wq[8];
#pragma unroll
    for (int m = 0; m < 8; ++m)
        Wq[m] = *(const float4*)(Wwhh + (long)rq * HH + (4 * m + q4) * 4);

    // Ww_hh rows 128..383 -> LDS, swizzled 16B blocks (bijective per row)
    for (int idx = t; idx < 256 * 128; idx += 512) {
        int r = idx >> 7, c = idx & 127;
        int cblk = c >> 2;
        int sb = cblk ^ (r & 7) ^ ((cblk >> 4) << 2);
        WwL[r * 128 + (sb << 2) + (c & 3)] = Wwhh[(long)(128 + r) * HH + c];
    }
    // per-thread E1 stream row (W_hh rows 0..383; waves 6-7 have none)
    const float4* wrow4 = (const float4*)(Whh + (long)(t < G3 ? t : 0) * HH);

    float* st = state + (long)b * 4480;  // cring 1024 | wwh 3072 | whh 384
    if (c0 == 0) {
        for (int idx = t; idx < 8 * 132; idx += 512) ((float*)cring)[idx] = 0.f;
        for (int idx = t; idx < 8 * 388; idx += 512) ((float*)wwh)[idx] = 0.f;
        for (int idx = t; idx < G3; idx += 512) whh[idx] = 0.f;
    } else {
        for (int idx = t; idx < 1024; idx += 512) cring[idx >> 7][idx & 127] = st[idx];
        for (int idx = t; idx < 3072; idx += 512) wwh[idx / 384][idx % 384] = st[1024 + idx];
        for (int idx = t; idx < 384; idx += 512) whh[idx] = st[4096 + idx];
    }
    barrier_();

    const long gwstep = (long)KK * G3;        // 3072
    const float* gwB = gwT + (long)b * CH * gwstep + (long)kB * G3 + 2 * lane;
    const long g3base = (long)b * CH * G3;
    const long axbase = (long)b * CH * HH;

    // ---- prefetch (step c0)
    float2 pA = *(const float2*)(gwB);
    float2 pF = *(const float2*)(gwB + 128);
    float2 pG = *(const float2*)(gwB + 256);
    int rs = gstarts[(b * TT + c0) * KK + kB];
    int rm = gmask  [(b * TT + c0) * KK + kB];
    float pg0 = g3x[g3base + rq];
    float pg1 = g3x[g3base + rq + 128];
    float pg2 = g3x[g3base + rq + 256];
    float pax = axb[axbase + rq];

    for (int j = c0; j < c0 + CH; ++j) {
        const int lt = j - c0;
        const int slot = rs & 7;                 // wave-uniform
        const bool valid = (rm != 0);
        const float2 cA = pA, cF = pF, cG = pG;
        const float dg0 = pg0, dg1 = pg1, dg2 = pg2, dax = pax;

        if (lane == 0) vmkF[kB] = valid ? 1.0f : 0.0f;

        // prefetch next step (loads stay in flight across raw barriers)
        if (lt + 1 < CH) {
            const float* gw = gwB + (long)(lt + 1) * gwstep;
            pA = *(const float2*)(gw);
            pF = *(const float2*)(gw + 128);
            pG = *(const float2*)(gw + 256);
            rs = gstarts[(b * TT + j + 1) * KK + kB];
            rm = gmask  [(b * TT + j + 1) * KK + kB];
            pg0 = g3x[g3base + (long)(lt + 1) * G3 + rq];
            pg1 = g3x[g3base + (long)(lt + 1) * G3 + rq + 128];
            pg2 = g3x[g3base + (long)(lt + 1) * G3 + rq + 256];
            pax = axb[axbase + (long)(lt + 1) * HH + rq];
        }

        // ---- Phase B: word-LSTM cells; wave kB handles k=kB, 2 rows/lane
        {
            const int r2 = 2 * lane;
            float2 wi = *(const float2*)&wwh[slot][r2];
            float2 wf = *(const float2*)&wwh[slot][r2 + 128];
            float2 wg = *(const float2*)&wwh[slot][r2 + 256];
            float2 cs = *(const float2*)&cring[slot][r2];
            float2 cw;
            cw.x = fsig_(cF.x + wf.x) * cs.x + fsig_(cA.x + wi.x) * ftanh_(cG.x + wg.x);
            cw.y = fsig_(cF.y + wf.y) * cs.y + fsig_(cA.y + wi.y) * ftanh_(cG.y + wg.y);
            *(float2*)&cwS[kB][r2] = cw;
        }
        barrier_();

        // block-wide mask weights (broadcast reads)
        const float4 vk0 = *(const float4*)&vmkF[0];
        const float4 vk1 = *(const float4*)&vmkF[4];
        const float vmk[8] = {vk0.x, vk0.y, vk0.z, vk0.w, vk1.x, vk1.y, vk1.z, vk1.w};
        const bool hw_any = (vk0.x + vk0.y + vk0.z + vk0.w + vk1.x + vk1.y + vk1.z + vk1.w) > 0.f;

        // ---- Phase C: masked alpha aggregation; quad-interleaved, conflict-free
        float sumw = 0.f, sumwc = 0.f;
#pragma unroll
        for (int k = 0; k < 8; ++k) {
            if (vmk[k] != 0.f) {                 // wave-uniform branch
                float a0 = 0.f, a1 = 0.f;
#pragma unroll
                for (int i = 0; i < 8; i += 2) {
                    float4 c0v = *(const float4*)&cwS[k][16 * i + 4 * q4];
                    float4 c1v = *(const float4*)&cwS[k][16 * (i + 1) + 4 * q4];
                    a0 += WAr[4*i]*c0v.x + WAr[4*i+1]*c0v.y + WAr[4*i+2]*c0v.z + WAr[4*i+3]*c0v.w;
                    a1 += WAr[4*i+4]*c1v.x + WAr[4*i+5]*c1v.y + WAr[4*i+6]*c1v.z + WAr[4*i+7]*c1v.w;
                }
                float acc = a0 + a1;
                acc += __shfl_xor(acc, 1);       // combine quarters
                acc += __shfl_xor(acc, 2);
                float al = fsig_(dax + acc);
                float w = fexp_(al);
                sumw += w;
                sumwc += w * cwS[k][rq];
            }
        }

        // ---- Phase D: char cell + merge (4 lanes/row redundant, q4==0 writes)
        float i_ = fsig_(dg0 + whh[rq]);
        float o_ = fsig_(dg1 + whh[rq + 128]);
        float g_ = ftanh_(dg2 + whh[rq + 256]);
        float cprev = cring[(j - 1) & 7][rq];
        float wc = fexp_(i_);
        float csoft = (wc * g_ + sumwc) / (wc + sumw);
        float ccpl = (1.f - i_) * cprev + i_ * g_;
        float cn = hw_any ? csoft : ccpl;
        float hn = o_ * ftanh_(cn);
        if (q4 == 0) {
            cring[j & 7][rq] = cn;
            hcur[rq] = hn;
            hs[((long)b * CH + lt) * HH + rq] = hn;
        }
        barrier_();

        const float4* h4 = (const float4*)hcur;

        // ---- Phase E-reg: Ww rows 0..127 from the quarter-stash (all threads)
        {
            float a0 = 0.f, a1 = 0.f, a2 = 0.f, a3 = 0.f;
#pragma unroll
            for (int m = 0; m < 8; ++m) {
                float4 w = Wq[m];
                float4 h = h4[4 * m + q4];
                a0 = fmaf(w.x, h.x, a0); a1 = fmaf(w.y, h.y, a1);
                a2 = fmaf(w.z, h.z, a2); a3 = fmaf(w.w, h.w, a3);
            }
            float e = (a0 + a1) + (a2 + a3);
            e += __shfl_xor(e, 1);               // combine quarters
            e += __shfl_xor(e, 2);
            if (q4 == 0) wwh[j & 7][rq] = e;     // Ww rows 0..127
        }

        // ---- Phase E1: stream W_hh row t from global (waves 0..5 only)
        if (t < G3) {
            float a0 = 0.f, a1 = 0.f, a2 = 0.f, a3 = 0.f;
#pragma unroll
            for (int q = 0; q < 8; ++q) {
                float4 w0 = wrow4[4*q],   h0 = h4[4*q];
                float4 w1 = wrow4[4*q+1], h1 = h4[4*q+1];
                float4 w2 = wrow4[4*q+2], h2 = h4[4*q+2];
                float4 w3 = wrow4[4*q+3], h3 = h4[4*q+3];
                a0 += w0.x*h0.x + w0.y*h0.y + w0.z*h0.z + w0.w*h0.w;
                a1 += w1.x*h1.x + w1.y*h1.y + w1.z*h1.z + w1.w*h1.w;
                a2 += w2.x*h2.x + w2.y*h2.y + w2.z*h2.z + w2.w*h2.w;
                a3 += w3.x*h3.x + w3.y*h3.y + w3.z*h3.z + w3.w*h3.w;
            }
            whh[t] = (a0 + a1) + (a2 + a3);      // W_hh @ h (next char gates)
        }

        // ---- Phase E2: LDS half-row dot (swizzled weights), pair-combine
        {
            float s0 = 0.f, s1 = 0.f;
#pragma unroll
            for (int cb = 0; cb < 16; cb += 2) {
                int cblk0 = cb | (hE << 4);
                int cblk1 = (cb + 1) | (hE << 4);
                int sb0 = cblk0 ^ (rr & 7) ^ (hE << 2);
                int sb1 = cblk1 ^ (rr & 7) ^ (hE << 2);
                float4 w0 = *(const float4*)&WwL[rr * 128 + (sb0 << 2)];
                float4 w1 = *(const float4*)&WwL[rr * 128 + (sb1 << 2)];
                float4 h0 = h4[cblk0], h1 = h4[cblk1];
                s0 += w0.x*h0.x + w0.y*h0.y + w0.z*h0.z + w0.w*h0.w;
                s1 += w1.x*h1.x + w1.y*h1.y + w1.z*h1.z + w1.w*h1.w;
            }
            float s = s0 + s1;
            s += __shfl_xor(s, 1);               // combine halves
            if (hE == 0) wwh[j & 7][128 + rr] = s;  // Ww rows 128..383
        }
        barrier_();
    }

    // persist state for next chunk
    for (int idx = t; idx < 1024; idx += 512) st[idx] = cring[idx >> 7][idx & 127];
    for (int idx = t; idx < 3072; idx += 512) st[1024 + idx] = wwh[idx / 384][idx % 384];
    for (int idx = t; idx < 384; idx += 512) st[4096 + idx] = whh[idx];
}

// ---------------- kernel 3: logits + argmax (fwd==bwd, so fold W_tag halves)
__global__ __launch_bounds__(320, 1)
void tag_kernel(const float* __restrict__ hs, const float* __restrict__ Wtag,
                const float* __restrict__ btag, const int* __restrict__ maskp,
                int* __restrict__ out, int c0, int CH)
{
    __shared__ float ht[16][132];
    __shared__ float lg[16][20];
    const int tid = threadIdx.x;
    const int bpg = CH >> 4;
    const int b = blockIdx.x / bpg;
    const int tg = blockIdx.x % bpg;
    const int lt0 = tg * 16;

    for (int idx = tid; idx < 16 * 128; idx += 320)
        ht[idx >> 7][idx & 127] = hs[((long)b * CH + lt0 + (idx >> 7)) * HH + (idx & 127)];
    __syncthreads();

    {
        int tl = tid / 20, l = tid - tl * 20;
        float a = btag[l];
        const float* w0 = Wtag + (long)l * 256;
#pragma unroll
        for (int r = 0; r < 128; ++r) a += (w0[r] + w0[r + 128]) * ht[tl][r];
        lg[tl][l] = a;
    }
    __syncthreads();
    if (tid < 16) {
        float best = lg[tid][0];
        int bi = 0;
#pragma unroll
        for (int l = 1; l < NL; ++l) {
            float v = lg[tid][l];
            if (v > best) { best = v; bi = l; }   // first-max (np.argmax semantics)
        }
        int t = c0 + lt0 + tid;
        out[b * TT + t] = maskp[b * TT + t] * bi;
    }
}

extern "C" void kernel_launch(void* const* d_in, const int* in_sizes, int n_in,
                              void* d_out, int out_size, void* d_ws, size_t ws_size,
                              hipStream_t stream) {
    const int* word_inputs   = (const int*)d_in[0];
    const int* biword_inputs = (const int*)d_in[1];
    const int* gaz_word_ids  = (const int*)d_in[2];
    const int* gaz_starts    = (const int*)d_in[3];
    const int* gaz_mask      = (const int*)d_in[4];
    const int* maskp         = (const int*)d_in[5];
    const float* word_table   = (const float*)d_in[6];
    const float* biword_table = (const float*)d_in[7];
    const float* gaz_table    = (const float*)d_in[8];
    const float* W_ih   = (const float*)d_in[9];
    const float* W_hh   = (const float*)d_in[10];
    const float* b_lstm = (const float*)d_in[11];
    const float* Wa_ih  = (const float*)d_in[12];
    const float* Wa_hh  = (const float*)d_in[13];
    const float* b_alpha= (const float*)d_in[14];
    const float* Ww_ih  = (const float*)d_in[15];
    const float* Ww_hh  = (const float*)d_in[16];
    const float* b_word = (const float*)d_in[17];
    const float* W_tag  = (const float*)d_in[18];
    const float* b_tag  = (const float*)d_in[19];
    int* out = (int*)d_out;
    float* ws = (float*)d_ws;

    // choose T-chunk so workspace fits: bytes = 118784*CH + 143360
    int CH = 16;
    if      (ws_size >= 118784UL * 512 + 143360UL) CH = 512;
    else if (ws_size >= 118784UL * 128 + 143360UL) CH = 128;
    else if (ws_size >= 118784UL *  32 + 143360UL) CH = 32;

    float* g3x = ws;                               // B*CH*384
    float* axb = g3x + 8L * CH * 384;              // B*CH*128
    float* gwT = axb + 8L * CH * 128;              // B*CH*8*384
    float* hsb = gwT + 8L * CH * 3072;             // B*CH*128
    float* stb = hsb + 8L * CH * 128;              // B*4480

    for (int c0 = 0; c0 < TT; c0 += CH) {
        embed_gates_kernel<<<CH, 512, 0, stream>>>(word_inputs, biword_inputs,
                                                   word_table, biword_table,
                                                   W_ih, Wa_ih, b_lstm, b_alpha,
                                                   g3x, axb, c0, CH);
        gaz_gates_kernel<<<CH, 384, 0, stream>>>(gaz_word_ids, gaz_table,
                                                 Ww_ih, b_word, gwT, c0, CH);
        lattice_scan_kernel<<<BB, 512, 0, stream>>>(g3x, axb, gwT, gaz_starts, gaz_mask,
                                                    W_hh, Ww_hh, Wa_hh, hsb, stb, c0, CH);
        tag_kernel<<<CH / 2, 320, 0, stream>>>(hsb, W_tag, b_tag, maskp, out, c0, CH);
    }
}

// Round 16
// 1966.182 us; speedup vs baseline: 2.1774x; 2.1772x over previous
//
#include <hip/hip_runtime.h>
#include <hip/hip_bf16.h>

#define BB 8
#define TT 512
#define KK 8
#define HH 128
#define G3 384
#define DIN 100
#define DG 50
#define NL 20

#if __has_builtin(__builtin_amdgcn_rcpf)
#define RCP_(x) __builtin_amdgcn_rcpf(x)
#else
#define RCP_(x) (1.0f/(x))
#endif

__device__ __forceinline__ float fexp_(float x) { return __expf(x); }
__device__ __forceinline__ float fsig_(float x) { return RCP_(1.0f + __expf(-x)); }
__device__ __forceinline__ float ftanh_(float x) {
    float e = __expf(2.0f * x);          // saturates correctly: inf -> 1, 0 -> -1
    return 1.0f - 2.0f * RCP_(e + 1.0f);
}
// LDS-ordering barrier that does NOT drain vmcnt (prefetches stay in flight)
__device__ __forceinline__ void barrier_() {
    asm volatile("s_waitcnt lgkmcnt(0)\n\ts_barrier" ::: "memory");
}

// ---------------- kernel 1a: g3x = x @ W_ih^T + b_lstm ; alphax = x @ Wa_ih^T + b_alpha
__global__ __launch_bounds__(512, 1)
void embed_gates_kernel(const int* __restrict__ wid, const int* __restrict__ bwid,
                        const float* __restrict__ wtab, const float* __restrict__ bwtab,
                        const float* __restrict__ Wih, const float* __restrict__ Waih,
                        const float* __restrict__ bl, const float* __restrict__ ba,
                        float* __restrict__ g3x, float* __restrict__ axo,
                        int c0, int CH)
{
    __shared__ float xs[8][104];
    const int tid = threadIdx.x;
    const int bpg = CH >> 3;
    const int b = blockIdx.x / bpg;
    const int tg = blockIdx.x % bpg;
    const int t0 = c0 + tg * 8;

    for (int idx = tid; idx < 800; idx += 512) {
        int tt = idx / 100;
        int c = idx - tt * 100;
        int t = t0 + tt;
        float v;
        if (c < 50) v = wtab[(long)wid[b * TT + t] * 50 + c];
        else        v = bwtab[(long)bwid[b * TT + t] * 50 + (c - 50)];
        xs[tt][c] = v;
    }
    __syncthreads();

    const int row = tid;
    float w[100];
    const float* wr;
    float bias;
    if (row < G3) { wr = Wih + (long)row * DIN; bias = bl[row]; }
    else          { wr = Waih + (long)(row - G3) * DIN; bias = ba[row - G3]; }
    const float4* wr4 = (const float4*)wr;
#pragma unroll
    for (int q = 0; q < 25; ++q) {
        float4 v = wr4[q];
        w[4*q] = v.x; w[4*q+1] = v.y; w[4*q+2] = v.z; w[4*q+3] = v.w;
    }
#pragma unroll 1
    for (int tt = 0; tt < 8; ++tt) {
        float a = bias;
#pragma unroll
        for (int c = 0; c < 100; ++c) a += w[c] * xs[tt][c];
        int lt = t0 - c0 + tt;
        if (row < G3) g3x[((long)b * CH + lt) * G3 + row] = a;
        else          axo[((long)b * CH + lt) * HH + (row - G3)] = a;
    }
}

// ---------------- kernel 1b: gwT[b][t][k][384] = Ww_ih @ gaz_emb + b_word
__global__ __launch_bounds__(384, 1)
void gaz_gates_kernel(const int* __restrict__ gids, const float* __restrict__ gtab,
                      const float* __restrict__ Wwih, const float* __restrict__ bw,
                      float* __restrict__ gwT, int c0, int CH)
{
    __shared__ float ges[64][52];
    const int tid = threadIdx.x;
    const int bpg = CH >> 3;
    const int b = blockIdx.x / bpg;
    const int tg = blockIdx.x % bpg;
    const int t0 = c0 + tg * 8;

    for (int idx = tid; idx < 64 * 50; idx += 384) {
        int p = idx / 50;
        int c = idx - p * 50;
        int tt = p >> 3, k = p & 7;
        int gid = gids[((long)(b * TT + t0 + tt)) * KK + k];
        ges[p][c] = gtab[(long)gid * DG + c];
    }
    __syncthreads();

    const int row = tid;
    float w[50];
    const float2* wr2 = (const float2*)(Wwih + (long)row * DG);
#pragma unroll
    for (int q = 0; q < 25; ++q) { float2 v = wr2[q]; w[2*q] = v.x; w[2*q+1] = v.y; }
    const float bias = bw[row];
    const int lt0 = t0 - c0;
#pragma unroll 1
    for (int p = 0; p < 64; ++p) {
        float a = bias;
#pragma unroll
        for (int c = 0; c < 50; ++c) a += w[c] * ges[p][c];
        int tt = p >> 3, k = p & 7;
        gwT[((long)(b * CH + lt0 + tt) * KK + k) * G3 + row] = a;
    }
}

// ---------------- kernel 2: sequential lattice scan, one block per batch
// 512 threads = 8 waves = 2 waves/SIMD. BEST-KNOWN CONFIG (rounds 9-11,
// 1890 us scan): 160-float declared stash of which the allocator keeps ~120
// register-resident and streams ~40/thread from L1/L2-backed scratch, hidden
// under 2-wave TLP. Empirically dominant over: full AGPR residency (r13),
// full global streaming (r15), pipelined reg buffers (r14), multi-CU
// distribution (r12). Ww_hh rows 128..383 in LDS (128 KB, XOR-swizzled).
__global__ __attribute__((amdgpu_flat_work_group_size(512, 512), amdgpu_waves_per_eu(2, 2)))
void lattice_scan_kernel(const float* __restrict__ g3x, const float* __restrict__ axb,
                         const float* __restrict__ gwT, const int* __restrict__ gstarts,
                         const int* __restrict__ gmask,
                         const float* __restrict__ Whh, const float* __restrict__ Wwhh,
                         const float* __restrict__ Wahh,
                         float* __restrict__ hs, float* __restrict__ state,
                         int c0, int CH)
{
    __shared__ float cring[8][132];
    __shared__ float cwS[8][132];
    __shared__ float wwh[8][388];
    __shared__ float whh[G3];
    __shared__ float hcur[HH];
    __shared__ float vmkF[8];
    __shared__ float WwL[256 * 128];   // Ww_hh rows 128..383, swizzled

    const int t = threadIdx.x;
    const int b = blockIdx.x;
    const int lane = t & 63;
    const int kB = t >> 6;                 // wave id == gaz index k
    const int rq = t >> 2, q4 = t & 3;     // phase C/D mapping (row, quarter)
    const int rr = t >> 1, hE = t & 1;     // phase E LDS half-row mapping

    // ---- register weight stash (160 floats declared; ~120 stay resident)
    float W0[HH], WAr[32];
    {
        const float4* rp = (t < G3) ? (const float4*)(Whh + (long)t * HH)
                                    : (const float4*)(Wwhh + (long)(t - G3) * HH);
#pragma unroll
        for (int q = 0; q < 32; ++q) {
            float4 v = rp[q];
            W0[4*q] = v.x; W0[4*q+1] = v.y; W0[4*q+2] = v.z; W0[4*q+3] = v.w;
        }
#pragma unroll
        for (int i = 0; i < 8; ++i) {
            float4 v = *(const float4*)(Wahh + (long)rq * HH + 16 * i + 4 * q4);
            WAr[4*i]=v.x; WAr[4*i+1]=v.y; WAr[4*i+2]=v.z; WAr[4*i+3]=v.w;
        }
    }
    // Ww_hh rows 128..383 -> LDS, swizzled 16B blocks (bijective per row)
    for (int idx = t; idx < 256 * 128; idx += 512) {
        int r = idx >> 7, c = idx & 127;
        int cblk = c >> 2;
        int sb = cblk ^ (r & 7) ^ ((cblk >> 4) << 2);
        WwL[r * 128 + (sb << 2) + (c & 3)] = Wwhh[(long)(128 + r) * HH + c];
    }

    float* st = state + (long)b * 4480;  // cring 1024 | wwh 3072 | whh 384
    if (c0 == 0) {
        for (int idx = t; idx < 8 * 132; idx += 512) ((float*)cring)[idx] = 0.f;
        for (int idx = t; idx < 8 * 388; idx += 512) ((float*)wwh)[idx] = 0.f;
        for (int idx = t; idx < G3; idx += 512) whh[idx] = 0.f;
    } else {
        for (int idx = t; idx < 1024; idx += 512) cring[idx >> 7][idx & 127] = st[idx];
        for (int idx = t; idx < 3072; idx += 512) wwh[idx / 384][idx % 384] = st[1024 + idx];
        for (int idx = t; idx < 384; idx += 512) whh[idx] = st[4096 + idx];
    }
    barrier_();

    const long gwstep = (long)KK * G3;        // 3072
    const float* gwB = gwT + (long)b * CH * gwstep + (long)kB * G3 + 2 * lane;
    const long g3base = (long)b * CH * G3;
    const long axbase = (long)b * CH * HH;

    // ---- prefetch (step c0): phase-B float2 rows + uniform start/mask + char gates
    float2 pA = *(const float2*)(gwB);
    float2 pF = *(const float2*)(gwB + 128);
    float2 pG = *(const float2*)(gwB + 256);
    int rs = gstarts[(b * TT + c0) * KK + kB];
    int rm = gmask  [(b * TT + c0) * KK + kB];
    float pg0 = g3x[g3base + rq];
    float pg1 = g3x[g3base + rq + 128];
    float pg2 = g3x[g3base + rq + 256];
    float pax = axb[axbase + rq];

    for (int j = c0; j < c0 + CH; ++j) {
        const int lt = j - c0;
        const int slot = rs & 7;                 // wave-uniform
        const bool valid = (rm != 0);
        const float2 cA = pA, cF = pF, cG = pG;
        const float dg0 = pg0, dg1 = pg1, dg2 = pg2, dax = pax;

        if (lane == 0) vmkF[kB] = valid ? 1.0f : 0.0f;

        // prefetch next step (loads stay in flight across raw barriers)
        if (lt + 1 < CH) {
            const float* gw = gwB + (long)(lt + 1) * gwstep;
            pA = *(const float2*)(gw);
            pF = *(const float2*)(gw + 128);
            pG = *(const float2*)(gw + 256);
            rs = gstarts[(b * TT + j + 1) * KK + kB];
            rm = gmask  [(b * TT + j + 1) * KK + kB];
            pg0 = g3x[g3base + (long)(lt + 1) * G3 + rq];
            pg1 = g3x[g3base + (long)(lt + 1) * G3 + rq + 128];
            pg2 = g3x[g3base + (long)(lt + 1) * G3 + rq + 256];
            pax = axb[axbase + (long)(lt + 1) * HH + rq];
        }

        // ---- Phase B: word-LSTM cells; wave kB handles k=kB, 2 rows/lane
        {
            const int r2 = 2 * lane;
            float2 wi = *(const float2*)&wwh[slot][r2];
            float2 wf = *(const float2*)&wwh[slot][r2 + 128];
            float2 wg = *(const float2*)&wwh[slot][r2 + 256];
            float2 cs = *(const float2*)&cring[slot][r2];
            float2 cw;
            cw.x = fsig_(cF.x + wf.x) * cs.x + fsig_(cA.x + wi.x) * ftanh_(cG.x + wg.x);
            cw.y = fsig_(cF.y + wf.y) * cs.y + fsig_(cA.y + wi.y) * ftanh_(cG.y + wg.y);
            *(float2*)&cwS[kB][r2] = cw;
        }
        barrier_();

        // block-wide mask weights (broadcast reads)
        const float4 vk0 = *(const float4*)&vmkF[0];
        const float4 vk1 = *(const float4*)&vmkF[4];
        const float vmk[8] = {vk0.x, vk0.y, vk0.z, vk0.w, vk1.x, vk1.y, vk1.z, vk1.w};
        const bool hw_any = (vk0.x + vk0.y + vk0.z + vk0.w + vk1.x + vk1.y + vk1.z + vk1.w) > 0.f;

        // ---- Phase C: masked alpha aggregation; quad-interleaved, conflict-free
        float sumw = 0.f, sumwc = 0.f;
#pragma unroll
        for (int k = 0; k < 8; ++k) {
            if (vmk[k] != 0.f) {                 // wave-uniform branch
                float a0 = 0.f, a1 = 0.f;
#pragma unroll
                for (int i = 0; i < 8; i += 2) {
                    float4 c0v = *(const float4*)&cwS[k][16 * i + 4 * q4];
                    float4 c1v = *(const float4*)&cwS[k][16 * (i + 1) + 4 * q4];
                    a0 += WAr[4*i]*c0v.x + WAr[4*i+1]*c0v.y + WAr[4*i+2]*c0v.z + WAr[4*i+3]*c0v.w;
                    a1 += WAr[4*i+4]*c1v.x + WAr[4*i+5]*c1v.y + WAr[4*i+6]*c1v.z + WAr[4*i+7]*c1v.w;
                }
                float acc = a0 + a1;
                acc += __shfl_xor(acc, 1);       // combine quarters
                acc += __shfl_xor(acc, 2);
                float al = fsig_(dax + acc);
                float w = fexp_(al);
                sumw += w;
                sumwc += w * cwS[k][rq];
            }
        }

        // ---- Phase D: char cell + merge (4 lanes/row redundant, q4==0 writes)
        float i_ = fsig_(dg0 + whh[rq]);
        float o_ = fsig_(dg1 + whh[rq + 128]);
        float g_ = ftanh_(dg2 + whh[rq + 256]);
        float cprev = cring[(j - 1) & 7][rq];
        float wc = fexp_(i_);
        float csoft = (wc * g_ + sumwc) / (wc + sumw);
        float ccpl = (1.f - i_) * cprev + i_ * g_;
        float cn = hw_any ? csoft : ccpl;
        float hn = o_ * ftanh_(cn);
        if (q4 == 0) {
            cring[j & 7][rq] = cn;
            hcur[rq] = hn;
            hs[((long)b * CH + lt) * HH + rq] = hn;
        }
        barrier_();

        // ---- Phase E part 1: register row dot (broadcast h reads, no shuffles)
        {
            const float4* h4 = (const float4*)hcur;
            float a0 = 0.f, a1 = 0.f, a2 = 0.f, a3 = 0.f;
#pragma unroll
            for (int q = 0; q < 8; ++q) {
                float4 h0 = h4[4*q], h1 = h4[4*q+1], h2 = h4[4*q+2], h3 = h4[4*q+3];
                a0 += W0[16*q+0]*h0.x + W0[16*q+1]*h0.y + W0[16*q+2]*h0.z + W0[16*q+3]*h0.w;
                a1 += W0[16*q+4]*h1.x + W0[16*q+5]*h1.y + W0[16*q+6]*h1.z + W0[16*q+7]*h1.w;
                a2 += W0[16*q+8]*h2.x + W0[16*q+9]*h2.y + W0[16*q+10]*h2.z + W0[16*q+11]*h2.w;
                a3 += W0[16*q+12]*h3.x + W0[16*q+13]*h3.y + W0[16*q+14]*h3.z + W0[16*q+15]*h3.w;
            }
            float e0 = (a0 + a1) + (a2 + a3);
            if (t < G3) whh[t] = e0;             // W_hh @ h (next char gates)
            else        wwh[j & 7][t - G3] = e0; // Ww rows 0..127
        }
        // ---- Phase E part 2: LDS half-row dot (swizzled weights), pair-combine
        {
            const float4* h4 = (const float4*)hcur;
            float s0 = 0.f, s1 = 0.f;
#pragma unroll
            for (int cb = 0; cb < 16; cb += 2) {
                int cblk0 = cb | (hE << 4);
                int cblk1 = (cb + 1) | (hE << 4);
                int sb0 = cblk0 ^ (rr & 7) ^ (hE << 2);
                int sb1 = cblk1 ^ (rr & 7) ^ (hE << 2);
                float4 w0 = *(const float4*)&WwL[rr * 128 + (sb0 << 2)];
                float4 w1 = *(const float4*)&WwL[rr * 128 + (sb1 << 2)];
                float4 h0 = h4[cblk0], h1 = h4[cblk1];
                s0 += w0.x*h0.x + w0.y*h0.y + w0.z*h0.z + w0.w*h0.w;
                s1 += w1.x*h1.x + w1.y*h1.y + w1.z*h1.z + w1.w*h1.w;
            }
            float s = s0 + s1;
            s += __shfl_xor(s, 1);               // combine halves
            if (hE == 0) wwh[j & 7][128 + rr] = s;  // Ww rows 128..383
        }
        barrier_();
    }

    // persist state for next chunk
    for (int idx = t; idx < 1024; idx += 512) st[idx] = cring[idx >> 7][idx & 127];
    for (int idx = t; idx < 3072; idx += 512) st[1024 + idx] = wwh[idx / 384][idx % 384];
    for (int idx = t; idx < 384; idx += 512) st[4096 + idx] = whh[idx];
}

// ---------------- kernel 3: logits + argmax (fwd==bwd, so fold W_tag halves)
__global__ __launch_bounds__(320, 1)
void tag_kernel(const float* __restrict__ hs, const float* __restrict__ Wtag,
                const float* __restrict__ btag, const int* __restrict__ maskp,
                int* __restrict__ out, int c0, int CH)
{
    __shared__ float ht[16][132];
    __shared__ float lg[16][20];
    const int tid = threadIdx.x;
    const int bpg = CH >> 4;
    const int b = blockIdx.x / bpg;
    const int tg = blockIdx.x % bpg;
    const int lt0 = tg * 16;

    for (int idx = tid; idx < 16 * 128; idx += 320)
        ht[idx >> 7][idx & 127] = hs[((long)b * CH + lt0 + (idx >> 7)) * HH + (idx & 127)];
    __syncthreads();

    {
        int tl = tid / 20, l = tid - tl * 20;
        float a = btag[l];
        const float* w0 = Wtag + (long)l * 256;
#pragma unroll
        for (int r = 0; r < 128; ++r) a += (w0[r] + w0[r + 128]) * ht[tl][r];
        lg[tl][l] = a;
    }
    __syncthreads();
    if (tid < 16) {
        float best = lg[tid][0];
        int bi = 0;
#pragma unroll
        for (int l = 1; l < NL; ++l) {
            float v = lg[tid][l];
            if (v > best) { best = v; bi = l; }   // first-max (np.argmax semantics)
        }
        int t = c0 + lt0 + tid;
        out[b * TT + t] = maskp[b * TT + t] * bi;
    }
}

extern "C" void kernel_launch(void* const* d_in, const int* in_sizes, int n_in,
                              void* d_out, int out_size, void* d_ws, size_t ws_size,
                              hipStream_t stream) {
    const int* word_inputs   = (const int*)d_in[0];
    const int* biword_inputs = (const int*)d_in[1];
    const int* gaz_word_ids  = (const int*)d_in[2];
    const int* gaz_starts    = (const int*)d_in[3];
    const int* gaz_mask      = (const int*)d_in[4];
    const int* maskp         = (const int*)d_in[5];
    const float* word_table   = (const float*)d_in[6];
    const float* biword_table = (const float*)d_in[7];
    const float* gaz_table    = (const float*)d_in[8];
    const float* W_ih   = (const float*)d_in[9];
    const float* W_hh   = (const float*)d_in[10];
    const float* b_lstm = (const float*)d_in[11];
    const float* Wa_ih  = (const float*)d_in[12];
    const float* Wa_hh  = (const float*)d_in[13];
    const float* b_alpha= (const float*)d_in[14];
    const float* Ww_ih  = (const float*)d_in[15];
    const float* Ww_hh  = (const float*)d_in[16];
    const float* b_word = (const float*)d_in[17];
    const float* W_tag  = (const float*)d_in[18];
    const float* b_tag  = (const float*)d_in[19];
    int* out = (int*)d_out;
    float* ws = (float*)d_ws;

    // choose T-chunk so workspace fits: bytes = 118784*CH + 143360
    int CH = 16;
    if      (ws_size >= 118784UL * 512 + 143360UL) CH = 512;
    else if (ws_size >= 118784UL * 128 + 143360UL) CH = 128;
    else if (ws_size >= 118784UL *  32 + 143360UL) CH = 32;

    float* g3x = ws;                               // B*CH*384
    float* axb = g3x + 8L * CH * 384;              // B*CH*128
    float* gwT = axb + 8L * CH * 128;              // B*CH*8*384
    float* hsb = gwT + 8L * CH * 3072;             // B*CH*128
    float* stb = hsb + 8L * CH * 128;              // B*4480

    for (int c0 = 0; c0 < TT; c0 += CH) {
        embed_gates_kernel<<<CH, 512, 0, stream>>>(word_inputs, biword_inputs,
                                                   word_table, biword_table,
                                                   W_ih, Wa_ih, b_lstm, b_alpha,
                                                   g3x, axb, c0, CH);
        gaz_gates_kernel<<<CH, 384, 0, stream>>>(gaz_word_ids, gaz_table,
                                                 Ww_ih, b_word, gwT, c0, CH);
        lattice_scan_kernel<<<BB, 512, 0, stream>>>(g3x, axb, gwT, gaz_starts, gaz_mask,
                                                    W_hh, Ww_hh, Wa_hh, hsb, stb, c0, CH);
        tag_kernel<<<CH / 2, 320, 0, stream>>>(hsb, W_tag, b_tag, maskp, out, c0, CH);
    }
}